// Round 2
// baseline (1380.838 us; speedup 1.0000x reference)
//
#include <hip/hip_runtime.h>
#include <hip/hip_bf16.h>

typedef unsigned int u32;
typedef unsigned short u16;
typedef __attribute__((ext_vector_type(8))) short bf16x8;
typedef __attribute__((ext_vector_type(8))) unsigned short u16x8;
typedef __attribute__((ext_vector_type(4))) float f32x4;
typedef __attribute__((ext_vector_type(4))) float f4;

#define HS_TOTAL 33554432   // S*B*H
#define MAXTILES 2048

// ws layout (bytes):
//     0: u32 nseg counter
//  4096: u32 hist[513]
//  8192: u32 offs[513]
// 16384: f32 bias[1024]
//  1MB : u16 wpack[2][64][8][64][8]   (1MB)
//  2MB : u32 segs[131072]             (512KB)
//  2.5MB: u32 sorted[131072]          (512KB)

__device__ __forceinline__ u16 f2bf(float f) {
  u32 u = __builtin_bit_cast(u32, f);
  u += 0x7fffu + ((u >> 16) & 1u);
  return (u16)(u >> 16);
}
__device__ __forceinline__ float sigm(float x) {
  return __builtin_amdgcn_rcpf(1.f + __builtin_amdgcn_exp2f(-1.44269504088896f * x));
}
__device__ __forceinline__ float tanh_(float x) {
  return 1.f - 2.f * __builtin_amdgcn_rcpf(1.f + __builtin_amdgcn_exp2f(2.88539008177793f * x));
}

// ---------- prep: pack W_ih^T, W_hh^T into MFMA B-fragment order (bf16) + bias ----------
// wpack[blk = which*512 + nt*8 + kt][lane][j] = W[nt*16+(lane&15)][kt*32+(lane>>4)*8+j]
__global__ void k_pack(const float* __restrict__ Wih, const float* __restrict__ Whh,
                       const float* __restrict__ bih, const float* __restrict__ bhh,
                       u16* __restrict__ wpack, float* __restrict__ bias) {
  int blk = blockIdx.x;
  int ln = threadIdx.x;
  if (blk >= 1024) {  // bias tail blocks
    int g = (blk - 1024) * 64 + ln;
    bias[g] = bih[g] + bhh[g];
    return;
  }
  const float* W = (blk >> 9) ? Whh : Wih;
  int nt = (blk >> 3) & 63, kt = blk & 7;
  int g = nt * 16 + (ln & 15);
  int kb = kt * 32 + (ln >> 4) * 8;
  const float* src = W + g * 256 + kb;
  u16x8 v;
#pragma unroll
  for (int j = 0; j < 8; j++) v[j] = f2bf(src[j]);
  *(u16x8*)(wpack + (size_t)blk * 512 + ln * 8) = v;
}

// ---------- prep: segment extraction ----------
// seg record: b(8) | start(9)<<8 | len(10)<<17 | h0flag<<27
__global__ void k_segscan(const float* __restrict__ done, u32* __restrict__ cnt,
                          u32* __restrict__ hist, u32* __restrict__ segs) {
  __shared__ float ld[512][5];   // padded: bank-conflict-free column reads
  __shared__ u32 lhist[513];
  int t = threadIdx.x;
  for (int i = t; i < 513; i += 256) lhist[i] = 0;
  int b0 = blockIdx.x * 4;
  for (int s = t; s < 512; s += 256) {
    f4 v = *(const f4*)(done + s * 256 + b0);
    ld[s][0] = v[0]; ld[s][1] = v[1]; ld[s][2] = v[2]; ld[s][3] = v[3];
  }
  __syncthreads();
  int wv = t >> 6, ln = t & 63;
  int b = b0 + wv;
  u32 myrec[8];
  int mycnt = 0;
  for (int j = 0; j < 8; j++) {
    int s = ln * 8 + j;
    float d = ld[s][wv];
    bool bnd = (s == 0) || (d != 0.f);
    if (bnd) {
      int s2 = s + 1;
      while (s2 < 512 && ld[s2][wv] == 0.f) s2++;
      u32 len = (u32)(s2 - s);
      u32 h0f = (s == 0 && d == 0.f) ? 1u : 0u;
      myrec[mycnt++] = (u32)b | ((u32)s << 8) | (len << 17) | (h0f << 27);
    }
  }
  // wave-aggregate the append
  u32 incl = (u32)mycnt;
  for (int d = 1; d < 64; d <<= 1) {
    u32 o = (u32)__shfl_up((int)incl, d);
    if (ln >= d) incl += o;
  }
  u32 total = (u32)__shfl((int)incl, 63);
  u32 base = 0;
  if (ln == 0) base = atomicAdd(cnt, total);
  base = (u32)__shfl((int)base, 0);
  u32 off = base + incl - (u32)mycnt;
  for (int i = 0; i < mycnt; i++) {
    segs[off + i] = myrec[i];
    atomicAdd(&lhist[(myrec[i] >> 17) & 1023], 1u);
  }
  __syncthreads();
  for (int i = t; i < 513; i += 256)
    if (lhist[i]) atomicAdd(&hist[i], lhist[i]);
}

// ---------- prep: offsets for descending-length sort ----------
__global__ void k_prefix(const u32* __restrict__ hist, u32* __restrict__ offs) {
  __shared__ u32 h[513];
  int t = threadIdx.x;
  if (t < 513) h[t] = hist[t];
  __syncthreads();
  if (t < 513) {
    u32 s = 0;
    for (int l = t + 1; l < 513; l++) s += h[l];
    offs[t] = s;
  }
}

// ---------- prep: scatter into sorted order ----------
__global__ void k_scatter(const u32* __restrict__ cnt, const u32* __restrict__ segs,
                          u32* __restrict__ offs, u32* __restrict__ sorted) {
  __shared__ u32 lh[513];
  __shared__ u32 gb[513];
  int t = threadIdx.x;
  for (int i = t; i < 513; i += 512) lh[i] = 0;
  __syncthreads();
  u32 n = *cnt;
  u32 i = blockIdx.x * 512 + t;
  u32 rec = 0, lpos = 0;
  bool v = (i < n);
  if (v) {
    rec = segs[i];
    lpos = atomicAdd(&lh[(rec >> 17) & 1023], 1u);
  }
  __syncthreads();
  for (int j = t; j < 513; j += 512) gb[j] = lh[j] ? atomicAdd(&offs[j], lh[j]) : 0u;
  __syncthreads();
  if (v) sorted[gb[(rec >> 17) & 1023] + lpos] = rec;
}

// ---------- main: 64-segment tiles, 16 waves, 64 acc-floats/thread (no spill) ----------
// wave w owns gate-column slice j in [16w,16w+16); n-tiles nt = q*16+w, q=0..3.
// LDS byte mapping everywhere: byte = row*512 + ((2*col) ^ ((row&7)<<4)).
__global__ __launch_bounds__(1024, 1) void k_main(
    const float* __restrict__ inp, const float* __restrict__ h0,
    const float* __restrict__ c0, const u16* __restrict__ wpack,
    const float* __restrict__ bias, const u32* __restrict__ cnt,
    const u32* __restrict__ sorted, float* __restrict__ out) {
  __shared__ __align__(16) u16 Ax[64 * 256];
  __shared__ __align__(16) u16 Ah[64 * 256];
  __shared__ u32 meta[64];
  __shared__ int s_h0;

  u32 nseg = *cnt;
  u32 base = blockIdx.x * 64u;
  if (base >= nseg) return;
  int tid = threadIdx.x;
  if (tid == 0) s_h0 = 0;
  __syncthreads();
  if (tid < 64) {
    u32 i = base + (u32)tid;
    u32 rec = (i < nseg) ? sorted[i] : 0u;
    meta[tid] = rec;
    if ((rec >> 27) & 1u) s_h0 = 1;  // benign same-value race
  }
  __syncthreads();

  const int maxlen = (int)((meta[0] >> 17) & 1023u);
  const int has0 = s_h0;
  const int w = tid >> 6, lane = tid & 63;
  const int srow = tid >> 4, scg = tid & 15;
  const u32 srec = meta[srow];
  const int s_len = (int)((srec >> 17) & 1023u);
  const int s_b = (int)(srec & 255u);
  const int s_st = (int)((srec >> 8) & 511u);
  char* AxB = (char*)&Ax[0];
  char* AhB = (char*)&Ah[0];
  const int swzS = (srow & 7) << 4;
  const int jcol = w * 16 + (lane & 15);
  const int lhi4 = (lane >> 4) << 4;

  // init Ah: zeros, or h0 row for h0-carry segments
  {
    bool hh = ((srec >> 27) & 1u) != 0u;
    u16x8 lo = (u16x8){0, 0, 0, 0, 0, 0, 0, 0}, hi = lo;
    if (hh) {
      const f4* hp = (const f4*)(h0 + s_b * 256 + scg * 16);
      f4 a0 = hp[0], a1 = hp[1], a2 = hp[2], a3 = hp[3];
      lo = (u16x8){f2bf(a0[0]), f2bf(a0[1]), f2bf(a0[2]), f2bf(a0[3]),
                   f2bf(a1[0]), f2bf(a1[1]), f2bf(a1[2]), f2bf(a1[3])};
      hi = (u16x8){f2bf(a2[0]), f2bf(a2[1]), f2bf(a2[2]), f2bf(a2[3]),
                   f2bf(a3[0]), f2bf(a3[1]), f2bf(a3[2]), f2bf(a3[3])};
    }
    *(u16x8*)(AhB + srow * 512 + ((scg * 32) ^ swzS)) = lo;
    *(u16x8*)(AhB + srow * 512 + ((scg * 32 + 16) ^ swzS)) = hi;
  }
  // stage X row 0 (every real segment has len >= 1)
  if (s_len > 0) {
    const f4* p = (const f4*)(inp + ((size_t)(s_st * 256 + s_b)) * 256 + scg * 16);
    f4 x0 = __builtin_nontemporal_load(p);
    f4 x1 = __builtin_nontemporal_load(p + 1);
    f4 x2 = __builtin_nontemporal_load(p + 2);
    f4 x3 = __builtin_nontemporal_load(p + 3);
    u16x8 lo = (u16x8){f2bf(x0[0]), f2bf(x0[1]), f2bf(x0[2]), f2bf(x0[3]),
                       f2bf(x1[0]), f2bf(x1[1]), f2bf(x1[2]), f2bf(x1[3])};
    u16x8 hi = (u16x8){f2bf(x2[0]), f2bf(x2[1]), f2bf(x2[2]), f2bf(x2[3]),
                       f2bf(x3[0]), f2bf(x3[1]), f2bf(x3[2]), f2bf(x3[3])};
    *(u16x8*)(AxB + srow * 512 + ((scg * 32) ^ swzS)) = lo;
    *(u16x8*)(AxB + srow * 512 + ((scg * 32 + 16) ^ swzS)) = hi;
  }

  // per-thread state: c for 16 rows x 1 col, bias for 4 gates
  float c_reg[4][4];
  float bias_r[4];
#pragma unroll
  for (int q = 0; q < 4; q++) bias_r[q] = bias[q * 256 + jcol];
#pragma unroll
  for (int mt = 0; mt < 4; mt++)
#pragma unroll
    for (int reg = 0; reg < 4; reg++) {
      int m = mt * 16 + ((lane >> 4) << 2) + reg;
      u32 rr = meta[m];
      c_reg[mt][reg] = ((rr >> 27) & 1u) ? c0[(rr & 255u) * 256 + jcol] : 0.f;
    }
  __syncthreads();

  const u16* wp0 = wpack;
  const u16* wp1 = wpack + (size_t)512 * 512;

  for (int r = 0; r < maxlen; r++) {
    f32x4 acc[4][4];
#pragma unroll
    for (int mt = 0; mt < 4; mt++)
#pragma unroll
      for (int q = 0; q < 4; q++) {
        float bv = bias_r[q];
        acc[mt][q] = (f32x4){bv, bv, bv, bv};
      }

    // ---- x-pass: gates += X * Wih^T ----
#pragma unroll
    for (int kt = 0; kt < 8; kt++) {
      bf16x8 a[4];
#pragma unroll
      for (int mt = 0; mt < 4; mt++) {
        int row = mt * 16 + (lane & 15);
        a[mt] = *(const bf16x8*)(AxB + row * 512 + ((kt * 64 + lhi4) ^ ((row & 7) << 4)));
      }
#pragma unroll
      for (int q = 0; q < 4; q++) {
        int nt = q * 16 + w;
        bf16x8 bq = *(const bf16x8*)(wp0 + ((size_t)(nt * 8 + kt) * 64 + lane) * 8);
#pragma unroll
        for (int mt = 0; mt < 4; mt++)
          acc[mt][q] = __builtin_amdgcn_mfma_f32_16x16x32_bf16(a[mt], bq, acc[mt][q], 0, 0, 0);
      }
    }
    // ---- h-pass: gates += H * Whh^T ----
    if (r > 0 || has0) {
#pragma unroll
      for (int kt = 0; kt < 8; kt++) {
        bf16x8 a[4];
#pragma unroll
        for (int mt = 0; mt < 4; mt++) {
          int row = mt * 16 + (lane & 15);
          a[mt] = *(const bf16x8*)(AhB + row * 512 + ((kt * 64 + lhi4) ^ ((row & 7) << 4)));
        }
#pragma unroll
        for (int q = 0; q < 4; q++) {
          int nt = q * 16 + w;
          bf16x8 bq = *(const bf16x8*)(wp1 + ((size_t)(nt * 8 + kt) * 64 + lane) * 8);
#pragma unroll
          for (int mt = 0; mt < 4; mt++)
            acc[mt][q] = __builtin_amdgcn_mfma_f32_16x16x32_bf16(a[mt], bq, acc[mt][q], 0, 0, 0);
        }
      }
    }
    __syncthreads();  // all reads of Ax/Ah done before writes below

    // ---- T14: issue next-row global loads early, hide under activation ----
    bool stg = (r + 1 < s_len);
    f4 x0, x1, x2, x3;
    if (stg) {
      const f4* p = (const f4*)(inp + ((size_t)((s_st + r + 1) * 256 + s_b)) * 256 + scg * 16);
      x0 = __builtin_nontemporal_load(p);
      x1 = __builtin_nontemporal_load(p + 1);
      x2 = __builtin_nontemporal_load(p + 2);
      x3 = __builtin_nontemporal_load(p + 3);
    }

    // ---- activations + state update + writes ----
#pragma unroll
    for (int mt = 0; mt < 4; mt++)
#pragma unroll
      for (int reg = 0; reg < 4; reg++) {
        int m = mt * 16 + ((lane >> 4) << 2) + reg;
        u32 rr = meta[m];
        int len = (int)((rr >> 17) & 1023u);
        if (r < len) {
          int bb = (int)(rr & 255u);
          int s = (int)((rr >> 8) & 511u) + r;
          float iv = acc[mt][0][reg];
          float fv = acc[mt][1][reg];
          float gv = acc[mt][2][reg];
          float ov = acc[mt][3][reg];
          float cn = sigm(fv) * c_reg[mt][reg] + sigm(iv) * tanh_(gv);
          float hn = sigm(ov) * tanh_(cn);
          c_reg[mt][reg] = cn;
          u32 oidx = ((u32)s << 16) | ((u32)bb << 8) | (u32)jcol;
          __builtin_nontemporal_store(hn, out + oidx);
          *((u16*)(AhB + m * 512 + ((2 * jcol) ^ ((m & 7) << 4)))) = f2bf(hn);
          if (s == 511) {
            out[HS_TOTAL + bb * 256 + jcol] = hn;
            out[HS_TOTAL + 65536 + bb * 256 + jcol] = cn;
          }
        }
      }

    if (stg) {
      u16x8 lo = (u16x8){f2bf(x0[0]), f2bf(x0[1]), f2bf(x0[2]), f2bf(x0[3]),
                         f2bf(x1[0]), f2bf(x1[1]), f2bf(x1[2]), f2bf(x1[3])};
      u16x8 hi = (u16x8){f2bf(x2[0]), f2bf(x2[1]), f2bf(x2[2]), f2bf(x2[3]),
                         f2bf(x3[0]), f2bf(x3[1]), f2bf(x3[2]), f2bf(x3[3])};
      *(u16x8*)(AxB + srow * 512 + ((scg * 32) ^ swzS)) = lo;
      *(u16x8*)(AxB + srow * 512 + ((scg * 32 + 16) ^ swzS)) = hi;
    }
    __syncthreads();  // Ah/Ax writes visible for next step
  }
}

extern "C" void kernel_launch(void* const* d_in, const int* in_sizes, int n_in,
                              void* d_out, int out_size, void* d_ws, size_t ws_size,
                              hipStream_t stream) {
  const float* inp = (const float*)d_in[0];
  const float* h0 = (const float*)d_in[1];
  const float* c0 = (const float*)d_in[2];
  const float* done = (const float*)d_in[3];
  const float* Wih = (const float*)d_in[4];
  const float* Whh = (const float*)d_in[5];
  const float* bih = (const float*)d_in[6];
  const float* bhh = (const float*)d_in[7];
  float* out = (float*)d_out;

  char* W = (char*)d_ws;
  u32* cnt = (u32*)W;
  u32* hist = (u32*)(W + 4096);
  u32* offs = (u32*)(W + 8192);
  float* bias = (float*)(W + 16384);
  u16* wpack = (u16*)(W + (1 << 20));
  u32* segs = (u32*)(W + (2 << 20));
  u32* sorted = (u32*)(W + (2 << 20) + (1 << 19));

  hipMemsetAsync(d_ws, 0, 8192, stream);
  k_pack<<<1040, 64, 0, stream>>>(Wih, Whh, bih, bhh, wpack, bias);
  k_segscan<<<64, 256, 0, stream>>>(done, cnt, hist, segs);
  k_prefix<<<1, 1024, 0, stream>>>(hist, offs);
  k_scatter<<<256, 512, 0, stream>>>(cnt, segs, offs, sorted);
  k_main<<<MAXTILES, 1024, 0, stream>>>(inp, h0, c0, wpack, bias, cnt, sorted, out);
}

// Round 3
// 631.619 us; speedup vs baseline: 2.1862x; 2.1862x over previous
//
#include <hip/hip_runtime.h>
#include <hip/hip_bf16.h>

typedef unsigned int u32;
typedef unsigned short u16;
typedef __attribute__((ext_vector_type(8))) short bf16x8;
typedef __attribute__((ext_vector_type(8))) unsigned short u16x8;
typedef __attribute__((ext_vector_type(4))) float f32x4;
typedef __attribute__((ext_vector_type(4))) float f4;

#define HS_TOTAL 33554432   // S*B*H
#define MAXTILES 2048

// ws layout (bytes):
//     0: u32 nseg counter
//  4096: u32 hist[513]
//  8192: u32 offs[513]
// 16384: f32 bias[1024]
//  1MB : u16 wpack[2][64][8][64][8]   (1MB)
//  2MB : u32 segs[131072]             (512KB)
//  2.5MB: u32 sorted[131072]          (512KB)

__device__ __forceinline__ u16 f2bf(float f) {
  u32 u = __builtin_bit_cast(u32, f);
  u += 0x7fffu + ((u >> 16) & 1u);
  return (u16)(u >> 16);
}
__device__ __forceinline__ float sigm(float x) {
  return __builtin_amdgcn_rcpf(1.f + __builtin_amdgcn_exp2f(-1.44269504088896f * x));
}
__device__ __forceinline__ float tanh_(float x) {
  return 1.f - 2.f * __builtin_amdgcn_rcpf(1.f + __builtin_amdgcn_exp2f(2.88539008177793f * x));
}

// ---------- prep: pack W_ih^T, W_hh^T into MFMA B-fragment order (bf16) + bias ----------
// wpack[blk = which*512 + nt*8 + kt][lane][j] = W[nt*16+(lane&15)][kt*32+(lane>>4)*8+j]
__global__ void k_pack(const float* __restrict__ Wih, const float* __restrict__ Whh,
                       const float* __restrict__ bih, const float* __restrict__ bhh,
                       u16* __restrict__ wpack, float* __restrict__ bias) {
  int blk = blockIdx.x;
  int ln = threadIdx.x;
  if (blk >= 1024) {  // bias tail blocks
    int g = (blk - 1024) * 64 + ln;
    bias[g] = bih[g] + bhh[g];
    return;
  }
  const float* W = (blk >> 9) ? Whh : Wih;
  int nt = (blk >> 3) & 63, kt = blk & 7;
  int g = nt * 16 + (ln & 15);
  int kb = kt * 32 + (ln >> 4) * 8;
  const float* src = W + g * 256 + kb;
  u16x8 v;
#pragma unroll
  for (int j = 0; j < 8; j++) v[j] = f2bf(src[j]);
  *(u16x8*)(wpack + (size_t)blk * 512 + ln * 8) = v;
}

// ---------- prep: segment extraction ----------
// seg record: b(8) | start(9)<<8 | len(10)<<17 | h0flag<<27
__global__ void k_segscan(const float* __restrict__ done, u32* __restrict__ cnt,
                          u32* __restrict__ hist, u32* __restrict__ segs) {
  __shared__ float ld[512][5];   // padded: bank-conflict-free column reads
  __shared__ u32 lhist[513];
  int t = threadIdx.x;
  for (int i = t; i < 513; i += 256) lhist[i] = 0;
  int b0 = blockIdx.x * 4;
  for (int s = t; s < 512; s += 256) {
    f4 v = *(const f4*)(done + s * 256 + b0);
    ld[s][0] = v[0]; ld[s][1] = v[1]; ld[s][2] = v[2]; ld[s][3] = v[3];
  }
  __syncthreads();
  int wv = t >> 6, ln = t & 63;
  int b = b0 + wv;
  u32 myrec[8];
  int mycnt = 0;
  for (int j = 0; j < 8; j++) {
    int s = ln * 8 + j;
    float d = ld[s][wv];
    bool bnd = (s == 0) || (d != 0.f);
    if (bnd) {
      int s2 = s + 1;
      while (s2 < 512 && ld[s2][wv] == 0.f) s2++;
      u32 len = (u32)(s2 - s);
      u32 h0f = (s == 0 && d == 0.f) ? 1u : 0u;
      myrec[mycnt++] = (u32)b | ((u32)s << 8) | (len << 17) | (h0f << 27);
    }
  }
  u32 incl = (u32)mycnt;
  for (int d = 1; d < 64; d <<= 1) {
    u32 o = (u32)__shfl_up((int)incl, d);
    if (ln >= d) incl += o;
  }
  u32 total = (u32)__shfl((int)incl, 63);
  u32 base = 0;
  if (ln == 0) base = atomicAdd(cnt, total);
  base = (u32)__shfl((int)base, 0);
  u32 off = base + incl - (u32)mycnt;
  for (int i = 0; i < mycnt; i++) {
    segs[off + i] = myrec[i];
    atomicAdd(&lhist[(myrec[i] >> 17) & 1023], 1u);
  }
  __syncthreads();
  for (int i = t; i < 513; i += 256)
    if (lhist[i]) atomicAdd(&hist[i], lhist[i]);
}

// ---------- prep: offsets for descending-length sort ----------
__global__ void k_prefix(const u32* __restrict__ hist, u32* __restrict__ offs) {
  __shared__ u32 h[513];
  int t = threadIdx.x;
  if (t < 513) h[t] = hist[t];
  __syncthreads();
  if (t < 513) {
    u32 s = 0;
    for (int l = t + 1; l < 513; l++) s += h[l];
    offs[t] = s;
  }
}

// ---------- prep: scatter into sorted order ----------
__global__ void k_scatter(const u32* __restrict__ cnt, const u32* __restrict__ segs,
                          u32* __restrict__ offs, u32* __restrict__ sorted) {
  __shared__ u32 lh[513];
  __shared__ u32 gb[513];
  int t = threadIdx.x;
  for (int i = t; i < 513; i += 512) lh[i] = 0;
  __syncthreads();
  u32 n = *cnt;
  u32 i = blockIdx.x * 512 + t;
  u32 rec = 0, lpos = 0;
  bool v = (i < n);
  if (v) {
    rec = segs[i];
    lpos = atomicAdd(&lh[(rec >> 17) & 1023], 1u);
  }
  __syncthreads();
  for (int j = t; j < 513; j += 512) gb[j] = lh[j] ? atomicAdd(&offs[j], lh[j]) : 0u;
  __syncthreads();
  if (v) sorted[gb[(rec >> 17) & 1023] + lpos] = rec;
}

// ---------- main: 64-segment tiles, 8 waves, 1 block/CU -> 256-reg budget ----------
// wave w owns gate-column slice j in [32w,32w+32); n-tiles nt = q*16 + w*2 + t2.
// c state in LDS (frees 32 regs); LDS 131KB forces 1 block/CU (2 waves/SIMD).
__global__ __launch_bounds__(512, 2) void k_main(
    const float* __restrict__ inp, const float* __restrict__ h0,
    const float* __restrict__ c0, const u16* __restrict__ wpack,
    const float* __restrict__ bias, const u32* __restrict__ cnt,
    const u32* __restrict__ sorted, float* __restrict__ out) {
  __shared__ __align__(16) u16 Ax[64 * 256];   // 32 KB
  __shared__ __align__(16) u16 Ah[64 * 256];   // 32 KB
  __shared__ float Cs[64 * 257];               // 64.25 KB, padded stride
  __shared__ u32 meta[64];
  __shared__ int s_h0;

  u32 nseg = *cnt;
  u32 base = blockIdx.x * 64u;
  if (base >= nseg) return;
  int tid = threadIdx.x;
  if (tid == 0) s_h0 = 0;
  __syncthreads();
  if (tid < 64) {
    u32 i = base + (u32)tid;
    u32 rec = (i < nseg) ? sorted[i] : 0u;
    meta[tid] = rec;
    if ((rec >> 27) & 1u) s_h0 = 1;  // benign same-value race
  }
  __syncthreads();

  const int maxlen = (int)((meta[0] >> 17) & 1023u);
  const int has0 = s_h0;
  const int w = tid >> 6, lane = tid & 63;
  const int srow = tid >> 3, scg = tid & 7;
  const u32 srec = meta[srow];
  const int s_len = (int)((srec >> 17) & 1023u);
  const int s_b = (int)(srec & 255u);
  const int s_st = (int)((srec >> 8) & 511u);
  char* AxB = (char*)&Ax[0];
  char* AhB = (char*)&Ah[0];
  const int swzS = (srow & 7) << 4;
  const int l15 = lane & 15, lhi = lane >> 4;
  const int lhi16 = lhi << 4;
  const int aswz = (lane & 7) << 4;

  // ---- init Ah (zeros or h0) and Ax row 0; each thread: row srow, cols [32*scg, 32*scg+32) ----
  {
    bool hh = ((srec >> 27) & 1u) != 0u;
    const f4* hp = (const f4*)(h0 + s_b * 256 + scg * 32);
#pragma unroll
    for (int u = 0; u < 4; u++) {
      u16x8 v = (u16x8){0, 0, 0, 0, 0, 0, 0, 0};
      if (hh) {
        f4 a0 = hp[2 * u], a1 = hp[2 * u + 1];
        v = (u16x8){f2bf(a0[0]), f2bf(a0[1]), f2bf(a0[2]), f2bf(a0[3]),
                    f2bf(a1[0]), f2bf(a1[1]), f2bf(a1[2]), f2bf(a1[3])};
      }
      *(u16x8*)(AhB + srow * 512 + ((scg * 64 + u * 16) ^ swzS)) = v;
    }
  }
  if (s_len > 0) {
    const f4* p = (const f4*)(inp + ((size_t)(s_st * 256 + s_b)) * 256 + scg * 32);
#pragma unroll
    for (int u = 0; u < 4; u++) {
      f4 x0 = __builtin_nontemporal_load(p + 2 * u);
      f4 x1 = __builtin_nontemporal_load(p + 2 * u + 1);
      u16x8 v = (u16x8){f2bf(x0[0]), f2bf(x0[1]), f2bf(x0[2]), f2bf(x0[3]),
                        f2bf(x1[0]), f2bf(x1[1]), f2bf(x1[2]), f2bf(x1[3])};
      *(u16x8*)(AxB + srow * 512 + ((scg * 64 + u * 16) ^ swzS)) = v;
    }
  } else {
    u16x8 z = (u16x8){0, 0, 0, 0, 0, 0, 0, 0};
#pragma unroll
    for (int u = 0; u < 4; u++)
      *(u16x8*)(AxB + srow * 512 + ((scg * 64 + u * 16) ^ swzS)) = z;
  }
  // ---- init Cs from c0 (h0-carry) or zero ----
  for (int i = tid; i < 16384; i += 512) {
    int m = i >> 8, j = i & 255;
    u32 rr = meta[m];
    Cs[m * 257 + j] = ((rr >> 27) & 1u) ? c0[(rr & 255u) * 256 + j] : 0.f;
  }
  float bias_r[4][2];
#pragma unroll
  for (int q = 0; q < 4; q++)
#pragma unroll
    for (int t2 = 0; t2 < 2; t2++)
      bias_r[q][t2] = bias[q * 256 + w * 32 + t2 * 16 + l15];
  __syncthreads();

  // weight fragment base for this lane/wave: + q*65536 + t2*4096 + kt*512 (u16 units)
  const u16* wl = wpack + lane * 8 + w * 8192;

  for (int r = 0; r < maxlen; r++) {
    f32x4 acc[4][4][2];
#pragma unroll
    for (int mt = 0; mt < 4; mt++)
#pragma unroll
      for (int q = 0; q < 4; q++)
#pragma unroll
        for (int t2 = 0; t2 < 2; t2++) {
          float bv = bias_r[q][t2];
          acc[mt][q][t2] = (f32x4){bv, bv, bv, bv};
        }

    // ---- x-pass ----
#pragma unroll 1
    for (int kt = 0; kt < 8; kt++) {
      bf16x8 a[4];
#pragma unroll
      for (int mt = 0; mt < 4; mt++)
        a[mt] = *(const bf16x8*)(AxB + (mt * 16 + l15) * 512 + ((kt * 64 + lhi16) ^ aswz));
#pragma unroll
      for (int q = 0; q < 4; q++)
#pragma unroll
        for (int t2 = 0; t2 < 2; t2++) {
          bf16x8 bq = *(const bf16x8*)(wl + q * 65536 + t2 * 4096 + kt * 512);
#pragma unroll
          for (int mt = 0; mt < 4; mt++)
            acc[mt][q][t2] =
                __builtin_amdgcn_mfma_f32_16x16x32_bf16(a[mt], bq, acc[mt][q][t2], 0, 0, 0);
        }
    }
    // ---- h-pass ----
    if (r > 0 || has0) {
#pragma unroll 1
      for (int kt = 0; kt < 8; kt++) {
        bf16x8 a[4];
#pragma unroll
        for (int mt = 0; mt < 4; mt++)
          a[mt] = *(const bf16x8*)(AhB + (mt * 16 + l15) * 512 + ((kt * 64 + lhi16) ^ aswz));
#pragma unroll
        for (int q = 0; q < 4; q++)
#pragma unroll
          for (int t2 = 0; t2 < 2; t2++) {
            bf16x8 bq = *(const bf16x8*)(wl + 262144 + q * 65536 + t2 * 4096 + kt * 512);
#pragma unroll
            for (int mt = 0; mt < 4; mt++)
              acc[mt][q][t2] =
                  __builtin_amdgcn_mfma_f32_16x16x32_bf16(a[mt], bq, acc[mt][q][t2], 0, 0, 0);
          }
      }
    }
    __syncthreads();  // all reads of Ax/Ah done before writes below

    // ---- T14: issue next-row global loads early, hide under activation ----
    bool stg = (r + 1 < s_len);
    f4 x[8];
    if (stg) {
      const f4* p = (const f4*)(inp + ((size_t)((s_st + r + 1) * 256 + s_b)) * 256 + scg * 32);
#pragma unroll
      for (int u = 0; u < 8; u++) x[u] = __builtin_nontemporal_load(p + u);
    }

    // ---- activations + state update + writes ----
#pragma unroll
    for (int mt = 0; mt < 4; mt++)
#pragma unroll
      for (int reg = 0; reg < 4; reg++) {
        int m = mt * 16 + lhi * 4 + reg;
        u32 rr = meta[m];
        int len = (int)((rr >> 17) & 1023u);
        if (r < len) {
          int bb = (int)(rr & 255u);
          int s = (int)((rr >> 8) & 511u) + r;
#pragma unroll
          for (int t2 = 0; t2 < 2; t2++) {
            int j = w * 32 + t2 * 16 + l15;
            float iv = acc[mt][0][t2][reg];
            float fv = acc[mt][1][t2][reg];
            float gv = acc[mt][2][t2][reg];
            float ov = acc[mt][3][t2][reg];
            float cp = Cs[m * 257 + j];
            float cn = sigm(fv) * cp + sigm(iv) * tanh_(gv);
            float hn = sigm(ov) * tanh_(cn);
            Cs[m * 257 + j] = cn;
            __builtin_nontemporal_store(hn, out + ((size_t)(s * 256 + bb)) * 256 + j);
            *((u16*)(AhB + m * 512 + ((2 * j) ^ ((m & 7) << 4)))) = f2bf(hn);
            if (s == 511) {
              out[HS_TOTAL + bb * 256 + j] = hn;
              out[HS_TOTAL + 65536 + bb * 256 + j] = cn;
            }
          }
        }
      }

    if (stg) {
#pragma unroll
      for (int u = 0; u < 4; u++) {
        f4 x0 = x[2 * u], x1 = x[2 * u + 1];
        u16x8 v = (u16x8){f2bf(x0[0]), f2bf(x0[1]), f2bf(x0[2]), f2bf(x0[3]),
                          f2bf(x1[0]), f2bf(x1[1]), f2bf(x1[2]), f2bf(x1[3])};
        *(u16x8*)(AxB + srow * 512 + ((scg * 64 + u * 16) ^ swzS)) = v;
      }
    }
    __syncthreads();  // Ah/Ax writes visible for next step
  }
}

extern "C" void kernel_launch(void* const* d_in, const int* in_sizes, int n_in,
                              void* d_out, int out_size, void* d_ws, size_t ws_size,
                              hipStream_t stream) {
  const float* inp = (const float*)d_in[0];
  const float* h0 = (const float*)d_in[1];
  const float* c0 = (const float*)d_in[2];
  const float* done = (const float*)d_in[3];
  const float* Wih = (const float*)d_in[4];
  const float* Whh = (const float*)d_in[5];
  const float* bih = (const float*)d_in[6];
  const float* bhh = (const float*)d_in[7];
  float* out = (float*)d_out;

  char* W = (char*)d_ws;
  u32* cnt = (u32*)W;
  u32* hist = (u32*)(W + 4096);
  u32* offs = (u32*)(W + 8192);
  float* bias = (float*)(W + 16384);
  u16* wpack = (u16*)(W + (1 << 20));
  u32* segs = (u32*)(W + (2 << 20));
  u32* sorted = (u32*)(W + (2 << 20) + (1 << 19));

  hipMemsetAsync(d_ws, 0, 8192, stream);
  k_pack<<<1040, 64, 0, stream>>>(Wih, Whh, bih, bhh, wpack, bias);
  k_segscan<<<64, 256, 0, stream>>>(done, cnt, hist, segs);
  k_prefix<<<1, 1024, 0, stream>>>(hist, offs);
  k_scatter<<<256, 512, 0, stream>>>(cnt, segs, offs, sorted);
  k_main<<<MAXTILES, 512, 0, stream>>>(inp, h0, c0, wpack, bias, cnt, sorted, out);
}

// Round 5
// 607.412 us; speedup vs baseline: 2.2733x; 1.0399x over previous
//
#include <hip/hip_runtime.h>
#include <hip/hip_bf16.h>

typedef unsigned int u32;
typedef unsigned short u16;
typedef __attribute__((ext_vector_type(8))) short bf16x8;
typedef __attribute__((ext_vector_type(8))) unsigned short u16x8;
typedef __attribute__((ext_vector_type(4))) float f32x4;
typedef __attribute__((ext_vector_type(4))) float f4;

#define HS_TOTAL 33554432   // S*B*H
#define MAXTILES 2048

// ws layout (bytes):
//     0: u32 nseg counter
//  4096: u32 hist[513]
//  8192: u32 offs[513]
// 16384: f32 bias[1024]
//  1MB : u16 wpack[64 nt][16 kt][64 lane][8]   (1MB)  kt 0-7 = Wih, 8-15 = Whh
//  2MB : u32 segs[131072]             (512KB)
//  2.5MB: u32 sorted[131072]          (512KB)
//  4MB : u16 inp_bf[S*B*256]          (64MB)   [big path only]

__device__ __forceinline__ u16 f2bf(float f) {
  u32 u = __builtin_bit_cast(u32, f);
  u += 0x7fffu + ((u >> 16) & 1u);
  return (u16)(u >> 16);
}
__device__ __forceinline__ float sigm(float x) {
  return __builtin_amdgcn_rcpf(1.f + __builtin_amdgcn_exp2f(-1.44269504088896f * x));
}
__device__ __forceinline__ float tanh_(float x) {
  return 1.f - 2.f * __builtin_amdgcn_rcpf(1.f + __builtin_amdgcn_exp2f(2.88539008177793f * x));
}

// ---------- prep: convert inp f32 -> bf16 ----------
__global__ void k_conv(const float* __restrict__ in, u16* __restrict__ outb) {
  size_t i = ((size_t)blockIdx.x * 256 + threadIdx.x) * 8;
  const f4* p = (const f4*)(in + i);
  f4 x0 = __builtin_nontemporal_load(p);
  f4 x1 = __builtin_nontemporal_load(p + 1);
  u16x8 v = (u16x8){f2bf(x0[0]), f2bf(x0[1]), f2bf(x0[2]), f2bf(x0[3]),
                    f2bf(x1[0]), f2bf(x1[1]), f2bf(x1[2]), f2bf(x1[3])};
  *(u16x8*)(outb + i) = v;
}

// ---------- prep: pack weights into [nt][ktm][lane][8] bf16 + bias ----------
// frag(nt,ktm,lane)[j] = W[nt*16+(lane&15)][(ktm&7)*32+(lane>>4)*8+j], W = ktm<8 ? Wih : Whh
__global__ void k_pack(const float* __restrict__ Wih, const float* __restrict__ Whh,
                       const float* __restrict__ bih, const float* __restrict__ bhh,
                       u16* __restrict__ wpack, float* __restrict__ bias) {
  int blk = blockIdx.x;
  int ln = threadIdx.x;
  if (blk >= 1024) {  // bias tail blocks
    int g = (blk - 1024) * 64 + ln;
    bias[g] = bih[g] + bhh[g];
    return;
  }
  int nt = blk >> 4, ktm = blk & 15;
  const float* W = (ktm >> 3) ? Whh : Wih;
  int g = nt * 16 + (ln & 15);
  int kb = (ktm & 7) * 32 + (ln >> 4) * 8;
  const float* src = W + g * 256 + kb;
  u16x8 v;
#pragma unroll
  for (int j = 0; j < 8; j++) v[j] = f2bf(src[j]);
  *(u16x8*)(wpack + (size_t)blk * 512 + ln * 8) = v;
}

// ---------- prep: segment extraction ----------
// seg record: b(8) | start(9)<<8 | len(10)<<17 | h0flag<<27
__global__ void k_segscan(const float* __restrict__ done, u32* __restrict__ cnt,
                          u32* __restrict__ hist, u32* __restrict__ segs) {
  __shared__ float ld[512][5];
  __shared__ u32 lhist[513];
  int t = threadIdx.x;
  for (int i = t; i < 513; i += 256) lhist[i] = 0;
  int b0 = blockIdx.x * 4;
  for (int s = t; s < 512; s += 256) {
    f4 v = *(const f4*)(done + s * 256 + b0);
    ld[s][0] = v[0]; ld[s][1] = v[1]; ld[s][2] = v[2]; ld[s][3] = v[3];
  }
  __syncthreads();
  int wv = t >> 6, ln = t & 63;
  int b = b0 + wv;
  u32 myrec[8];
  int mycnt = 0;
  for (int j = 0; j < 8; j++) {
    int s = ln * 8 + j;
    float d = ld[s][wv];
    bool bnd = (s == 0) || (d != 0.f);
    if (bnd) {
      int s2 = s + 1;
      while (s2 < 512 && ld[s2][wv] == 0.f) s2++;
      u32 len = (u32)(s2 - s);
      u32 h0f = (s == 0 && d == 0.f) ? 1u : 0u;
      myrec[mycnt++] = (u32)b | ((u32)s << 8) | (len << 17) | (h0f << 27);
    }
  }
  u32 incl = (u32)mycnt;
  for (int d = 1; d < 64; d <<= 1) {
    u32 o = (u32)__shfl_up((int)incl, d);
    if (ln >= d) incl += o;
  }
  u32 total = (u32)__shfl((int)incl, 63);
  u32 base = 0;
  if (ln == 0) base = atomicAdd(cnt, total);
  base = (u32)__shfl((int)base, 0);
  u32 off = base + incl - (u32)mycnt;
  for (int i = 0; i < mycnt; i++) {
    segs[off + i] = myrec[i];
    atomicAdd(&lhist[(myrec[i] >> 17) & 1023], 1u);
  }
  __syncthreads();
  for (int i = t; i < 513; i += 256)
    if (lhist[i]) atomicAdd(&hist[i], lhist[i]);
}

// ---------- prep: offsets for descending-length sort ----------
__global__ void k_prefix(const u32* __restrict__ hist, u32* __restrict__ offs) {
  __shared__ u32 h[513];
  int t = threadIdx.x;
  if (t < 513) h[t] = hist[t];
  __syncthreads();
  if (t < 513) {
    u32 s = 0;
    for (int l = t + 1; l < 513; l++) s += h[l];
    offs[t] = s;
  }
}

// ---------- prep: scatter into sorted order ----------
__global__ void k_scatter(const u32* __restrict__ cnt, const u32* __restrict__ segs,
                          u32* __restrict__ offs, u32* __restrict__ sorted) {
  __shared__ u32 lh[513];
  __shared__ u32 gb[513];
  int t = threadIdx.x;
  for (int i = t; i < 513; i += 512) lh[i] = 0;
  __syncthreads();
  u32 n = *cnt;
  u32 i = blockIdx.x * 512 + t;
  u32 rec = 0, lpos = 0;
  bool v = (i < n);
  if (v) {
    rec = segs[i];
    lpos = atomicAdd(&lh[(rec >> 17) & 1023], 1u);
  }
  __syncthreads();
  for (int j = t; j < 513; j += 512) gb[j] = lh[j] ? atomicAdd(&offs[j], lh[j]) : 0u;
  __syncthreads();
  if (v) sorted[gb[(rec >> 17) & 1023] + lpos] = rec;
}

// ---------- main (big path): merged K=512 pass, async x-staging, weight dbuf ----------
// wave w owns gate cols j in [32w,32w+32); frag f=(q,t2): nt = q*16 + w*2 + t2.
// LDS As[2][64][256] bf16 (x,h), swizzle byte ^= ((row&7)<<4); Cs f32 swizzled.
__global__ __launch_bounds__(512, 2) void k_main(
    const u16* __restrict__ inp_bf, const float* __restrict__ h0,
    const float* __restrict__ c0, const u16* __restrict__ wpack,
    const float* __restrict__ bias, const u32* __restrict__ cnt,
    const u32* __restrict__ sorted, float* __restrict__ out) {
  __shared__ __align__(16) u16 As[2][64][256];  // 64 KB
  __shared__ __align__(16) float Cs[64 * 256];  // 64 KB
  __shared__ u32 meta[64];
  __shared__ int s_h0;

  u32 nseg = *cnt;
  u32 base = blockIdx.x * 64u;
  if (base >= nseg) return;
  int tid = threadIdx.x;
  if (tid == 0) s_h0 = 0;
  __syncthreads();
  if (tid < 64) {
    u32 i = base + (u32)tid;
    u32 rec = (i < nseg) ? sorted[i] : 0u;
    meta[tid] = rec;
    if ((rec >> 27) & 1u) s_h0 = 1;
  }
  __syncthreads();

  const int maxlen = (int)((meta[0] >> 17) & 1023u);
  const int has0 = s_h0;
  const int w = tid >> 6, lane = tid & 63;
  const int l15 = lane & 15, lhi = lane >> 4;
  const int srow = tid >> 3, scg = tid & 7;
  const u32 srec = meta[srow];
  char* AsB = (char*)&As[0][0][0];
  char* CsB = (char*)&Cs[0];
  const int swzS = (srow & 7) << 4;

  // ---- init As[1] (h): zeros or h0 ----
  {
    bool hh = ((srec >> 27) & 1u) != 0u;
    const f4* hp = (const f4*)(h0 + (srec & 255u) * 256 + scg * 32);
#pragma unroll
    for (int u = 0; u < 4; u++) {
      u16x8 v = (u16x8){0, 0, 0, 0, 0, 0, 0, 0};
      if (hh) {
        f4 a0 = hp[2 * u], a1 = hp[2 * u + 1];
        v = (u16x8){f2bf(a0[0]), f2bf(a0[1]), f2bf(a0[2]), f2bf(a0[3]),
                    f2bf(a1[0]), f2bf(a1[1]), f2bf(a1[2]), f2bf(a1[3])};
      }
      *(u16x8*)(AsB + 32768 + srow * 512 + ((scg * 64 + u * 16) ^ swzS)) = v;
    }
  }
  // ---- init Cs (swizzled) ----
  for (int i = tid; i < 16384; i += 512) {
    int m = i >> 8, j = i & 255;
    u32 rr = meta[m];
    float cv = ((rr >> 27) & 1u) ? c0[(rr & 255u) * 256 + j] : 0.f;
    *(float*)(CsB + m * 1024 + ((4 * j) ^ ((m & 7) << 4))) = cv;
  }
  float bias_r[4][2];
#pragma unroll
  for (int q = 0; q < 4; q++)
#pragma unroll
    for (int t2 = 0; t2 < 2; t2++)
      bias_r[q][t2] = bias[q * 256 + w * 32 + t2 * 16 + l15];

  // ---- async x staging: 4 instrs/wave, 2 rows each, pre-swizzled global source ----
  const int strow0 = w * 8;           // this wave stages rows [w*8, w*8+8)
  const int sl31 = lane & 31;
  auto stage_x = [&](int r1) {
#pragma unroll
    for (int i = 0; i < 4; i++) {
      int row = strow0 + 2 * i + (lane >> 5);
      u32 rr = meta[row];
      int len = (int)((rr >> 17) & 1023u);
      u16* ldst = &As[0][strow0 + 2 * i][0];  // wave-uniform base
      if (r1 < len) {
        int bb = (int)(rr & 255u);
        int st = (int)((rr >> 8) & 511u);
        int srcoff = (sl31 * 16) ^ ((row & 7) << 4);
        const char* src =
            (const char*)(inp_bf + ((size_t)((st + r1) * 256 + bb)) * 256) + srcoff;
        __builtin_amdgcn_global_load_lds(
            (const __attribute__((address_space(1))) void*)src,
            (__attribute__((address_space(3))) void*)ldst, 16, 0, 0);
      }
    }
  };
  stage_x(0);
  __syncthreads();  // drains vmcnt -> As[0] row 0 ready

  // weight base for this wave/lane (u16 units); frag (q,t2,ktm): + q*131072 + t2*8192 + ktm*512
  const u16* wl = wpack + w * 16384 + lane * 8;

  f32x4 acc[4][4][2];
  bf16x8 wA[8], wB[8], afr[4];

  auto ldw = [&](bf16x8(&dst)[8], int ktm) {
#pragma unroll
    for (int f = 0; f < 8; f++)
      dst[f] = *(const bf16x8*)(wl + (f >> 1) * 131072 + (f & 1) * 8192 + ktm * 512);
  };
  auto lda = [&](int ktm) {
#pragma unroll
    for (int mt = 0; mt < 4; mt++) {
      int row = mt * 16 + l15;
      afr[mt] = *(const bf16x8*)(AsB + (ktm >> 3) * 32768 + row * 512 +
                                 (((ktm & 7) * 64 + lhi * 16) ^ ((row & 7) << 4)));
    }
  };
  auto domfma = [&](bf16x8(&wv)[8]) {
#pragma unroll
    for (int f = 0; f < 8; f++)
#pragma unroll
      for (int mt = 0; mt < 4; mt++)
        acc[mt][f >> 1][f & 1] =
            __builtin_amdgcn_mfma_f32_16x16x32_bf16(afr[mt], wv[f], acc[mt][f >> 1][f & 1], 0, 0, 0);
  };

  for (int r = 0; r < maxlen; r++) {
#pragma unroll
    for (int mt = 0; mt < 4; mt++)
#pragma unroll
      for (int q = 0; q < 4; q++)
#pragma unroll
        for (int t2 = 0; t2 < 2; t2++) {
          float bv = bias_r[q][t2];
          acc[mt][q][t2] = (f32x4){bv, bv, bv, bv};
        }

    const int ktlim = (r > 0 || has0) ? 16 : 8;
    ldw(wA, 0);
    for (int kt = 0; kt < ktlim; kt += 2) {
      ldw(wB, kt + 1);
      lda(kt);
      domfma(wA);
      if (kt + 2 < ktlim) ldw(wA, kt + 2);
      lda(kt + 1);
      domfma(wB);
    }
    __syncthreads();  // all As reads done

    stage_x(r + 1);   // async: lands before end-of-step barrier

    // ---- activations + state update + writes ----
#pragma unroll
    for (int mt = 0; mt < 4; mt++)
#pragma unroll
      for (int reg = 0; reg < 4; reg++) {
        int m = mt * 16 + lhi * 4 + reg;
        u32 rr = meta[m];
        int len = (int)((rr >> 17) & 1023u);
        if (r < len) {
          int bb = (int)(rr & 255u);
          int s = (int)((rr >> 8) & 511u) + r;
#pragma unroll
          for (int t2 = 0; t2 < 2; t2++) {
            int j = w * 32 + t2 * 16 + l15;
            float iv = acc[mt][0][t2][reg];
            float fv = acc[mt][1][t2][reg];
            float gv = acc[mt][2][t2][reg];
            float ov = acc[mt][3][t2][reg];
            float* cp = (float*)(CsB + m * 1024 + ((4 * j) ^ ((m & 7) << 4)));
            float cn = sigm(fv) * (*cp) + sigm(iv) * tanh_(gv);
            float hn = sigm(ov) * tanh_(cn);
            *cp = cn;
            __builtin_nontemporal_store(hn, out + ((size_t)(s * 256 + bb)) * 256 + j);
            *((u16*)(AsB + 32768 + m * 512 + ((2 * j) ^ ((m & 7) << 4)))) = f2bf(hn);
            if (s == 511) {
              out[HS_TOTAL + bb * 256 + j] = hn;
              out[HS_TOTAL + 65536 + bb * 256 + j] = cn;
            }
          }
        }
      }
    __syncthreads();  // As[1] writes + staged As[0] row r+1 visible
  }
}

// ---------- fallback (small ws): round-3 structure, new weight layout ----------
__global__ __launch_bounds__(512, 2) void k_main_small(
    const float* __restrict__ inp, const float* __restrict__ h0,
    const float* __restrict__ c0, const u16* __restrict__ wpack,
    const float* __restrict__ bias, const u32* __restrict__ cnt,
    const u32* __restrict__ sorted, float* __restrict__ out) {
  __shared__ __align__(16) u16 Ax[64 * 256];
  __shared__ __align__(16) u16 Ah[64 * 256];
  __shared__ float Cs[64 * 257];
  __shared__ u32 meta[64];
  __shared__ int s_h0;

  u32 nseg = *cnt;
  u32 base = blockIdx.x * 64u;
  if (base >= nseg) return;
  int tid = threadIdx.x;
  if (tid == 0) s_h0 = 0;
  __syncthreads();
  if (tid < 64) {
    u32 i = base + (u32)tid;
    u32 rec = (i < nseg) ? sorted[i] : 0u;
    meta[tid] = rec;
    if ((rec >> 27) & 1u) s_h0 = 1;
  }
  __syncthreads();

  const int maxlen = (int)((meta[0] >> 17) & 1023u);
  const int has0 = s_h0;
  const int w = tid >> 6, lane = tid & 63;
  const int srow = tid >> 3, scg = tid & 7;
  const u32 srec = meta[srow];
  const int s_len = (int)((srec >> 17) & 1023u);
  const int s_b = (int)(srec & 255u);
  const int s_st = (int)((srec >> 8) & 511u);
  char* AxB = (char*)&Ax[0];
  char* AhB = (char*)&Ah[0];
  const int swzS = (srow & 7) << 4;
  const int l15 = lane & 15, lhi = lane >> 4;
  const int lhi16 = lhi << 4;
  const int aswz = (lane & 7) << 4;

  {
    bool hh = ((srec >> 27) & 1u) != 0u;
    const f4* hp = (const f4*)(h0 + s_b * 256 + scg * 32);
#pragma unroll
    for (int u = 0; u < 4; u++) {
      u16x8 v = (u16x8){0, 0, 0, 0, 0, 0, 0, 0};
      if (hh) {
        f4 a0 = hp[2 * u], a1 = hp[2 * u + 1];
        v = (u16x8){f2bf(a0[0]), f2bf(a0[1]), f2bf(a0[2]), f2bf(a0[3]),
                    f2bf(a1[0]), f2bf(a1[1]), f2bf(a1[2]), f2bf(a1[3])};
      }
      *(u16x8*)(AhB + srow * 512 + ((scg * 64 + u * 16) ^ swzS)) = v;
    }
  }
  if (s_len > 0) {
    const f4* p = (const f4*)(inp + ((size_t)(s_st * 256 + s_b)) * 256 + scg * 32);
#pragma unroll
    for (int u = 0; u < 4; u++) {
      f4 x0 = __builtin_nontemporal_load(p + 2 * u);
      f4 x1 = __builtin_nontemporal_load(p + 2 * u + 1);
      u16x8 v = (u16x8){f2bf(x0[0]), f2bf(x0[1]), f2bf(x0[2]), f2bf(x0[3]),
                        f2bf(x1[0]), f2bf(x1[1]), f2bf(x1[2]), f2bf(x1[3])};
      *(u16x8*)(AxB + srow * 512 + ((scg * 64 + u * 16) ^ swzS)) = v;
    }
  } else {
    u16x8 z = (u16x8){0, 0, 0, 0, 0, 0, 0, 0};
#pragma unroll
    for (int u = 0; u < 4; u++)
      *(u16x8*)(AxB + srow * 512 + ((scg * 64 + u * 16) ^ swzS)) = z;
  }
  for (int i = tid; i < 16384; i += 512) {
    int m = i >> 8, j = i & 255;
    u32 rr = meta[m];
    Cs[m * 257 + j] = ((rr >> 27) & 1u) ? c0[(rr & 255u) * 256 + j] : 0.f;
  }
  float bias_r[4][2];
#pragma unroll
  for (int q = 0; q < 4; q++)
#pragma unroll
    for (int t2 = 0; t2 < 2; t2++)
      bias_r[q][t2] = bias[q * 256 + w * 32 + t2 * 16 + l15];
  __syncthreads();

  const u16* wl = wpack + w * 16384 + lane * 8;

  for (int r = 0; r < maxlen; r++) {
    f32x4 acc[4][4][2];
#pragma unroll
    for (int mt = 0; mt < 4; mt++)
#pragma unroll
      for (int q = 0; q < 4; q++)
#pragma unroll
        for (int t2 = 0; t2 < 2; t2++) {
          float bv = bias_r[q][t2];
          acc[mt][q][t2] = (f32x4){bv, bv, bv, bv};
        }

#pragma unroll 1
    for (int kt = 0; kt < 8; kt++) {
      bf16x8 a[4];
#pragma unroll
      for (int mt = 0; mt < 4; mt++)
        a[mt] = *(const bf16x8*)(AxB + (mt * 16 + l15) * 512 + ((kt * 64 + lhi16) ^ aswz));
#pragma unroll
      for (int q = 0; q < 4; q++)
#pragma unroll
        for (int t2 = 0; t2 < 2; t2++) {
          bf16x8 bq = *(const bf16x8*)(wl + q * 131072 + t2 * 8192 + kt * 512);
#pragma unroll
          for (int mt = 0; mt < 4; mt++)
            acc[mt][q][t2] =
                __builtin_amdgcn_mfma_f32_16x16x32_bf16(a[mt], bq, acc[mt][q][t2], 0, 0, 0);
        }
    }
    if (r > 0 || has0) {
#pragma unroll 1
      for (int kt = 0; kt < 8; kt++) {
        bf16x8 a[4];
#pragma unroll
        for (int mt = 0; mt < 4; mt++)
          a[mt] = *(const bf16x8*)(AhB + (mt * 16 + l15) * 512 + ((kt * 64 + lhi16) ^ aswz));
#pragma unroll
        for (int q = 0; q < 4; q++)
#pragma unroll
          for (int t2 = 0; t2 < 2; t2++) {
            bf16x8 bq = *(const bf16x8*)(wl + q * 131072 + t2 * 8192 + (kt + 8) * 512);
#pragma unroll
            for (int mt = 0; mt < 4; mt++)
              acc[mt][q][t2] =
                  __builtin_amdgcn_mfma_f32_16x16x32_bf16(a[mt], bq, acc[mt][q][t2], 0, 0, 0);
          }
      }
    }
    __syncthreads();

    bool stg = (r + 1 < s_len);
    f4 x[8];
    if (stg) {
      const f4* p = (const f4*)(inp + ((size_t)((s_st + r + 1) * 256 + s_b)) * 256 + scg * 32);
#pragma unroll
      for (int u = 0; u < 8; u++) x[u] = __builtin_nontemporal_load(p + u);
    }

#pragma unroll
    for (int mt = 0; mt < 4; mt++)
#pragma unroll
      for (int reg = 0; reg < 4; reg++) {
        int m = mt * 16 + lhi * 4 + reg;
        u32 rr = meta[m];
        int len = (int)((rr >> 17) & 1023u);
        if (r < len) {
          int bb = (int)(rr & 255u);
          int s = (int)((rr >> 8) & 511u) + r;
#pragma unroll
          for (int t2 = 0; t2 < 2; t2++) {
            int j = w * 32 + t2 * 16 + l15;
            float iv = acc[mt][0][t2][reg];
            float fv = acc[mt][1][t2][reg];
            float gv = acc[mt][2][t2][reg];
            float ov = acc[mt][3][t2][reg];
            float cp = Cs[m * 257 + j];
            float cn = sigm(fv) * cp + sigm(iv) * tanh_(gv);
            float hn = sigm(ov) * tanh_(cn);
            Cs[m * 257 + j] = cn;
            __builtin_nontemporal_store(hn, out + ((size_t)(s * 256 + bb)) * 256 + j);
            *((u16*)(AhB + m * 512 + ((2 * j) ^ ((m & 7) << 4)))) = f2bf(hn);
            if (s == 511) {
              out[HS_TOTAL + bb * 256 + j] = hn;
              out[HS_TOTAL + 65536 + bb * 256 + j] = cn;
            }
          }
        }
      }

    if (stg) {
#pragma unroll
      for (int u = 0; u < 4; u++) {
        f4 x0 = x[2 * u], x1 = x[2 * u + 1];
        u16x8 v = (u16x8){f2bf(x0[0]), f2bf(x0[1]), f2bf(x0[2]), f2bf(x0[3]),
                          f2bf(x1[0]), f2bf(x1[1]), f2bf(x1[2]), f2bf(x1[3])};
        *(u16x8*)(AxB + srow * 512 + ((scg * 64 + u * 16) ^ swzS)) = v;
      }
    }
    __syncthreads();
  }
}

extern "C" void kernel_launch(void* const* d_in, const int* in_sizes, int n_in,
                              void* d_out, int out_size, void* d_ws, size_t ws_size,
                              hipStream_t stream) {
  const float* inp = (const float*)d_in[0];
  const float* h0 = (const float*)d_in[1];
  const float* c0 = (const float*)d_in[2];
  const float* done = (const float*)d_in[3];
  const float* Wih = (const float*)d_in[4];
  const float* Whh = (const float*)d_in[5];
  const float* bih = (const float*)d_in[6];
  const float* bhh = (const float*)d_in[7];
  float* out = (float*)d_out;

  char* W = (char*)d_ws;
  u32* cnt = (u32*)W;
  u32* hist = (u32*)(W + 4096);
  u32* offs = (u32*)(W + 8192);
  float* bias = (float*)(W + 16384);
  u16* wpack = (u16*)(W + (1 << 20));
  u32* segs = (u32*)(W + (2 << 20));
  u32* sorted = (u32*)(W + (2 << 20) + (1 << 19));
  u16* inp_bf = (u16*)(W + (4 << 20));

  const bool big = ws_size >= (size_t)(4 + 65) * 1024 * 1024;

  hipMemsetAsync(d_ws, 0, 8192, stream);
  k_pack<<<1040, 64, 0, stream>>>(Wih, Whh, bih, bhh, wpack, bias);
  k_segscan<<<64, 256, 0, stream>>>(done, cnt, hist, segs);
  k_prefix<<<1, 1024, 0, stream>>>(hist, offs);
  k_scatter<<<256, 512, 0, stream>>>(cnt, segs, offs, sorted);
  if (big) {
    k_conv<<<16384, 256, 0, stream>>>(inp, inp_bf);
    k_main<<<MAXTILES, 512, 0, stream>>>(inp_bf, h0, c0, wpack, bias, cnt, sorted, out);
  } else {
    k_main_small<<<MAXTILES, 512, 0, stream>>>(inp, h0, c0, wpack, bias, cnt, sorted, out);
  }
}